// Round 3
// baseline (52.044 us; speedup 1.0000x reference)
//
#include <hip/hip_runtime.h>
#include <math.h>

#define NG      1024
#define IMG_H   128
#define IMG_W   128
#define NPIX    (IMG_H * IMG_W)
#define MIN_A   (1.0f / 255.0f)
#define LOG2E   1.4426950408889634f

// Record layout (per gaussian, after preprocess):
//  g0 = {mx, my, a2, b2}          a2 = -0.5*conicA*log2e, b2 = -conicB*log2e
//  g1 = {c2, op_eff, colR, colG}  c2 = -0.5*conicC*log2e
//  g2 = colB
// so  G = exp2( min(a2*dx^2 + c2*dy^2 + b2*dx*dy, 0) )

// ---------------------------------------------------------------------------
__device__ inline void project_one(
    int i,
    const float* __restrict__ pos, const float* __restrict__ cov,
    const float* __restrict__ col, const float* __restrict__ opa,
    const float* __restrict__ cm,
    float4& r0, float4& r1, float& r2, float& zret)
{
    const float R00 = cm[0], R01 = cm[1], R02 = cm[2],  T0 = cm[3];
    const float R10 = cm[4], R11 = cm[5], R12 = cm[6],  T1 = cm[7];
    const float R20 = cm[8], R21 = cm[9], R22 = cm[10], T2 = cm[11];

    const float p0 = pos[3*i], p1 = pos[3*i+1], p2 = pos[3*i+2];
    const float x = R00*p0 + R01*p1 + R02*p2 + T0;
    const float y = R10*p0 + R11*p1 + R12*p2 + T1;
    const float z = R20*p0 + R21*p1 + R22*p2 + T2;

    const float focal = 110.85125168440814f;   // 0.5*128/tan(pi/6)
    const float zc = fmaxf(z, 1e-6f);
    const float mx = focal * x / zc + 0.5f * IMG_W;
    const float my = focal * y / zc + 0.5f * IMG_H;

    const float c00 = cov[9*i+0], c01 = cov[9*i+1], c02 = cov[9*i+2];
    const float c10 = cov[9*i+3], c11 = cov[9*i+4], c12 = cov[9*i+5];
    const float c20 = cov[9*i+6], c21 = cov[9*i+7], c22 = cov[9*i+8];
    const float s00 = c00, s01 = 0.5f*(c01+c10), s02 = 0.5f*(c02+c20);
    const float s11 = c11, s12 = 0.5f*(c12+c21), s22 = c22;

    const float RS00 = R00*s00 + R01*s01 + R02*s02;
    const float RS01 = R00*s01 + R01*s11 + R02*s12;
    const float RS02 = R00*s02 + R01*s12 + R02*s22;
    const float RS10 = R10*s00 + R11*s01 + R12*s02;
    const float RS11 = R10*s01 + R11*s11 + R12*s12;
    const float RS12 = R10*s02 + R11*s12 + R12*s22;
    const float RS20 = R20*s00 + R21*s01 + R22*s02;
    const float RS21 = R20*s01 + R21*s11 + R22*s12;
    const float RS22 = R20*s02 + R21*s12 + R22*s22;
    const float CC00 = RS00*R00 + RS01*R01 + RS02*R02;
    const float CC01 = RS00*R10 + RS01*R11 + RS02*R12;
    const float CC02 = RS00*R20 + RS01*R21 + RS02*R22;
    const float CC11 = RS10*R10 + RS11*R11 + RS12*R12;
    const float CC12 = RS10*R20 + RS11*R21 + RS12*R22;
    const float CC20 = RS20*R00 + RS21*R01 + RS22*R02;
    const float CC21 = RS20*R10 + RS21*R11 + RS22*R12;
    const float CC22 = RS20*R20 + RS21*R21 + RS22*R22;

    const float j00 = focal / zc, j02 = -focal * x / (zc*zc);
    const float j11 = focal / zc, j12 = -focal * y / (zc*zc);

    const float v00 = CC00*j00 + CC02*j02;
    const float v02 = CC20*j00 + CC22*j02;
    const float v10 = CC01*j11 + CC02*j12;
    const float v11 = CC11*j11 + CC12*j12;
    const float v12 = CC21*j11 + CC22*j12;

    const float a  = j00*v00 + j02*v02 + 0.3f;
    const float b  = j00*v10 + j02*v12;
    const float cQ = j11*v11 + j12*v12 + 0.3f;

    const float det = a*cQ - b*b;
    const float det_safe = (det > 0.f) ? det : 1.f;
    const float conA =  cQ / det_safe;
    const float conB = -b  / det_safe;
    const float conC =  a  / det_safe;

    const bool  valid  = (z > 0.2f) && (det > 0.f);
    const float op_eff = valid ? opa[i] : 0.f;

    r0 = make_float4(mx, my, -0.5f*conA*LOG2E, -conB*LOG2E);
    r1 = make_float4(-0.5f*conC*LOG2E, op_eff, col[3*i], col[3*i+1]);
    r2 = col[3*i+2];
    zret = z;
}

// ---------------------------------------------------------------------------
// Kernel 1: projection, unsorted records. 4 blocks x 256.
// ---------------------------------------------------------------------------
__global__ __launch_bounds__(256) void gs_project(
    const float* __restrict__ pos, const float* __restrict__ cov,
    const float* __restrict__ col, const float* __restrict__ opa,
    const float* __restrict__ cm,
    float4* __restrict__ u0, float4* __restrict__ u1, float* __restrict__ u2,
    float* __restrict__ zout)
{
    const int i = blockIdx.x * 256 + threadIdx.x;
    float4 r0, r1; float r2, z;
    project_one(i, pos, cov, col, opa, cm, r0, r1, r2, z);
    u0[i] = r0; u1[i] = r1; u2[i] = r2; zout[i] = z;
}

// ---------------------------------------------------------------------------
// Kernel 2: stable rank-sort by z + scatter. 16 blocks x 64 (spread over CUs),
// z staged in LDS as float4 so the rank loop uses ds_read_b128.
// ---------------------------------------------------------------------------
__global__ __launch_bounds__(64) void gs_sort_scatter(
    const float* __restrict__ z,
    const float4* __restrict__ u0, const float4* __restrict__ u1,
    const float* __restrict__ u2,
    float4* __restrict__ g0, float4* __restrict__ g1, float* __restrict__ g2)
{
    __shared__ float4 zsh[NG / 4];
    const int tid = threadIdx.x;
    for (int j = tid; j < NG / 4; j += 64) zsh[j] = ((const float4*)z)[j];
    __syncthreads();

    const int i = blockIdx.x * 64 + tid;
    const float zi = z[i];
    int rank = 0;
    #pragma unroll 4
    for (int j4 = 0; j4 < NG / 4; ++j4) {
        const float4 v = zsh[j4];
        const int j = 4 * j4;
        rank += (v.x < zi || (v.x == zi && j + 0 < i)) ? 1 : 0;
        rank += (v.y < zi || (v.y == zi && j + 1 < i)) ? 1 : 0;
        rank += (v.z < zi || (v.z == zi && j + 2 < i)) ? 1 : 0;
        rank += (v.w < zi || (v.w == zi && j + 3 < i)) ? 1 : 0;
    }
    g0[rank] = u0[i]; g1[rank] = u1[i]; g2[rank] = u2[i];
}

// ---------------------------------------------------------------------------
// Kernel 3: per-(pixel-group, chunk) partial compositing.
// 4 pixels per thread: one LDS gaussian read feeds 4 pixels of compute.
// grid = (NPIX/(256*4), NCHUNK) = (16, 32) for GPC=32.
// ---------------------------------------------------------------------------
template<int GPC>
__global__ __launch_bounds__(256) void gs_raster_partial(
    const float4* __restrict__ g0, const float4* __restrict__ g1,
    const float*  __restrict__ g2, float4* __restrict__ part)
{
    __shared__ float4 s0[GPC];
    __shared__ float4 s1[GPC];
    __shared__ float  s2[GPC];

    const int tid  = threadIdx.x;
    const int k    = blockIdx.y;
    const int base = k * GPC;
    for (int j = tid; j < GPC; j += 256) {
        s0[j] = g0[base + j]; s1[j] = g1[base + j]; s2[j] = g2[base + j];
    }
    __syncthreads();

    const int t = blockIdx.x * 256 + tid;       // 0..4095
    float pxf[4], pyf[4];
    float T[4], cr[4], cg[4], cb[4];
    #pragma unroll
    for (int m = 0; m < 4; ++m) {
        const int p = t + m * 4096;
        pxf[m] = (float)(p & (IMG_W - 1)) + 0.5f;
        pyf[m] = (float)(p >> 7) + 0.5f;
        T[m] = 1.f; cr[m] = 0.f; cg[m] = 0.f; cb[m] = 0.f;
    }

    #pragma unroll 2
    for (int i = 0; i < GPC; ++i) {
        const float4 A = s0[i];            // mx, my, a2, b2
        const float4 B = s1[i];            // c2, op, colR, colG
        const float  C = s2[i];
        #pragma unroll
        for (int m = 0; m < 4; ++m) {
            const float dx = pxf[m] - A.x;
            const float dy = pyf[m] - A.y;
            const float pw = fminf(A.z*dx*dx + B.x*dy*dy + A.w*(dx*dy), 0.f);
            const float G = __builtin_amdgcn_exp2f(pw);
            float alpha = fminf(B.y * G, 0.99f);
            alpha = (alpha >= MIN_A) ? alpha : 0.f;
            const float wT = alpha * T[m];
            cr[m] = fmaf(wT, B.z, cr[m]);
            cg[m] = fmaf(wT, B.w, cg[m]);
            cb[m] = fmaf(wT, C,   cb[m]);
            T[m] *= (1.f - alpha);
        }
    }

    #pragma unroll
    for (int m = 0; m < 4; ++m) {
        const int p = t + m * 4096;
        part[k * NPIX + p] = make_float4(cr[m], cg[m], cb[m], T[m]);
    }
}

// Direct fallback (no workspace): whole range, 4 px/thread, write out.
__global__ __launch_bounds__(256) void gs_raster_direct(
    const float4* __restrict__ g0, const float4* __restrict__ g1,
    const float*  __restrict__ g2, float* __restrict__ out)
{
    __shared__ float4 s0[NG];
    __shared__ float4 s1[NG];
    __shared__ float  s2[NG];

    const int tid = threadIdx.x;
    for (int j = tid; j < NG; j += 256) {
        s0[j] = g0[j]; s1[j] = g1[j]; s2[j] = g2[j];
    }
    __syncthreads();

    const int t = blockIdx.x * 256 + tid;
    float pxf[4], pyf[4], T[4], cr[4], cg[4], cb[4];
    #pragma unroll
    for (int m = 0; m < 4; ++m) {
        const int p = t + m * 4096;
        pxf[m] = (float)(p & (IMG_W - 1)) + 0.5f;
        pyf[m] = (float)(p >> 7) + 0.5f;
        T[m] = 1.f; cr[m] = 0.f; cg[m] = 0.f; cb[m] = 0.f;
    }
    for (int i = 0; i < NG; ++i) {
        const float4 A = s0[i];
        const float4 B = s1[i];
        const float  C = s2[i];
        #pragma unroll
        for (int m = 0; m < 4; ++m) {
            const float dx = pxf[m] - A.x;
            const float dy = pyf[m] - A.y;
            const float pw = fminf(A.z*dx*dx + B.x*dy*dy + A.w*(dx*dy), 0.f);
            const float G = __builtin_amdgcn_exp2f(pw);
            float alpha = fminf(B.y * G, 0.99f);
            alpha = (alpha >= MIN_A) ? alpha : 0.f;
            const float wT = alpha * T[m];
            cr[m] = fmaf(wT, B.z, cr[m]);
            cg[m] = fmaf(wT, B.w, cg[m]);
            cb[m] = fmaf(wT, C,   cb[m]);
            T[m] *= (1.f - alpha);
        }
    }
    #pragma unroll
    for (int m = 0; m < 4; ++m) {
        const int p = t + m * 4096;
        float* o = out + 3 * p;
        o[0] = cr[m]; o[1] = cg[m]; o[2] = cb[m];
    }
}

// ---------------------------------------------------------------------------
// Kernel 4: combine chunk partials front-to-back. 64 blocks x 256.
// ---------------------------------------------------------------------------
__global__ __launch_bounds__(256) void gs_combine(
    const float4* __restrict__ part, int nchunk, float* __restrict__ out)
{
    const int p = blockIdx.x * 256 + threadIdx.x;
    float T = 1.f, cr = 0.f, cg = 0.f, cb = 0.f;
    for (int k = 0; k < nchunk; ++k) {
        const float4 v = part[k * NPIX + p];
        cr = fmaf(T, v.x, cr);
        cg = fmaf(T, v.y, cg);
        cb = fmaf(T, v.z, cb);
        T *= v.w;
    }
    float* o = out + 3 * p;
    o[0] = cr; o[1] = cg; o[2] = cb;
}

// ---------------------------------------------------------------------------
extern "C" void kernel_launch(void* const* d_in, const int* in_sizes, int n_in,
                              void* d_out, int out_size, void* d_ws, size_t ws_size,
                              hipStream_t stream) {
    const float* pos = (const float*)d_in[0];
    const float* cov = (const float*)d_in[1];
    const float* col = (const float*)d_in[2];
    const float* opa = (const float*)d_in[3];
    const float* cm  = (const float*)d_in[4];

    char* ws = (char*)d_ws;
    // fixed record area: g0|g1|g2|u0|u1|u2|z  = 77824 B
    float4* g0 = (float4*)(ws);                 // 16384
    float4* g1 = (float4*)(ws + 16384);         // 16384
    float*  g2 = (float*) (ws + 32768);         //  4096
    float4* u0 = (float4*)(ws + 36864);         // 16384
    float4* u1 = (float4*)(ws + 53248);         // 16384
    float*  u2 = (float*) (ws + 69632);         //  4096
    float*  zz = (float*) (ws + 73728);         //  4096
    float4* part = (float4*)(ws + 77824);

    const size_t rec = 77824;
    const size_t per_chunk = (size_t)NPIX * 16;   // 256 KB

    int nchunk = 0;
    if      (ws_size >= rec + 32 * per_chunk) nchunk = 32;
    else if (ws_size >= rec + 16 * per_chunk) nchunk = 16;
    else if (ws_size >= rec +  8 * per_chunk) nchunk = 8;
    else if (ws_size >= rec +  4 * per_chunk) nchunk = 4;

    gs_project<<<NG/256, 256, 0, stream>>>(pos, cov, col, opa, cm, u0, u1, u2, zz);
    gs_sort_scatter<<<NG/64, 64, 0, stream>>>(zz, u0, u1, u2, g0, g1, g2);

    float* out = (float*)d_out;
    const int pix_blocks = NPIX / (256 * 4);   // 16
    if (nchunk == 32) {
        gs_raster_partial<NG/32><<<dim3(pix_blocks, 32), 256, 0, stream>>>(g0, g1, g2, part);
        gs_combine<<<NPIX/256, 256, 0, stream>>>(part, 32, out);
    } else if (nchunk == 16) {
        gs_raster_partial<NG/16><<<dim3(pix_blocks, 16), 256, 0, stream>>>(g0, g1, g2, part);
        gs_combine<<<NPIX/256, 256, 0, stream>>>(part, 16, out);
    } else if (nchunk == 8) {
        gs_raster_partial<NG/8><<<dim3(pix_blocks, 8), 256, 0, stream>>>(g0, g1, g2, part);
        gs_combine<<<NPIX/256, 256, 0, stream>>>(part, 8, out);
    } else if (nchunk == 4) {
        gs_raster_partial<NG/4><<<dim3(pix_blocks, 4), 256, 0, stream>>>(g0, g1, g2, part);
        gs_combine<<<NPIX/256, 256, 0, stream>>>(part, 4, out);
    } else {
        gs_raster_direct<<<pix_blocks, 256, 0, stream>>>(g0, g1, g2, out);
    }
}

// Round 4
// 42.381 us; speedup vs baseline: 1.2280x; 1.2280x over previous
//
#include <hip/hip_runtime.h>
#include <math.h>

#define NG      1024
#define IMG_H   128
#define IMG_W   128
#define NPIX    (IMG_H * IMG_W)
#define MIN_A   (1.0f / 255.0f)
#define LOG2E   1.4426950408889634f

// Record layout (per gaussian, sorted by z):
//  g0 = {mx, my, a2, b2}          a2 = -0.5*conicA*log2e, b2 = -conicB*log2e
//  g1 = {c2, op_eff, colR, colG}  c2 = -0.5*conicC*log2e
//  g2 = colB
// so  G = exp2( min(a2*dx^2 + c2*dy^2 + b2*dx*dy, 0) )

// ---------------------------------------------------------------------------
__device__ inline void project_one(
    int i,
    const float* __restrict__ pos, const float* __restrict__ cov,
    const float* __restrict__ col, const float* __restrict__ opa,
    const float* __restrict__ cm,
    float4& r0, float4& r1, float& r2)
{
    const float R00 = cm[0], R01 = cm[1], R02 = cm[2],  T0 = cm[3];
    const float R10 = cm[4], R11 = cm[5], R12 = cm[6],  T1 = cm[7];
    const float R20 = cm[8], R21 = cm[9], R22 = cm[10], T2 = cm[11];

    const float p0 = pos[3*i], p1 = pos[3*i+1], p2 = pos[3*i+2];
    const float x = R00*p0 + R01*p1 + R02*p2 + T0;
    const float y = R10*p0 + R11*p1 + R12*p2 + T1;
    const float z = R20*p0 + R21*p1 + R22*p2 + T2;

    const float focal = 110.85125168440814f;   // 0.5*128/tan(pi/6)
    const float zc = fmaxf(z, 1e-6f);
    const float mx = focal * x / zc + 0.5f * IMG_W;
    const float my = focal * y / zc + 0.5f * IMG_H;

    const float c00 = cov[9*i+0], c01 = cov[9*i+1], c02 = cov[9*i+2];
    const float c10 = cov[9*i+3], c11 = cov[9*i+4], c12 = cov[9*i+5];
    const float c20 = cov[9*i+6], c21 = cov[9*i+7], c22 = cov[9*i+8];
    const float s00 = c00, s01 = 0.5f*(c01+c10), s02 = 0.5f*(c02+c20);
    const float s11 = c11, s12 = 0.5f*(c12+c21), s22 = c22;

    const float RS00 = R00*s00 + R01*s01 + R02*s02;
    const float RS01 = R00*s01 + R01*s11 + R02*s12;
    const float RS02 = R00*s02 + R01*s12 + R02*s22;
    const float RS10 = R10*s00 + R11*s01 + R12*s02;
    const float RS11 = R10*s01 + R11*s11 + R12*s12;
    const float RS12 = R10*s02 + R11*s12 + R12*s22;
    const float RS20 = R20*s00 + R21*s01 + R22*s02;
    const float RS21 = R20*s01 + R21*s11 + R22*s12;
    const float RS22 = R20*s02 + R21*s12 + R22*s22;
    const float CC00 = RS00*R00 + RS01*R01 + RS02*R02;
    const float CC01 = RS00*R10 + RS01*R11 + RS02*R12;
    const float CC02 = RS00*R20 + RS01*R21 + RS02*R22;
    const float CC11 = RS10*R10 + RS11*R11 + RS12*R12;
    const float CC12 = RS10*R20 + RS11*R21 + RS12*R22;
    const float CC20 = RS20*R00 + RS21*R01 + RS22*R02;
    const float CC21 = RS20*R10 + RS21*R11 + RS22*R12;
    const float CC22 = RS20*R20 + RS21*R21 + RS22*R22;

    const float j00 = focal / zc, j02 = -focal * x / (zc*zc);
    const float j11 = focal / zc, j12 = -focal * y / (zc*zc);

    const float v00 = CC00*j00 + CC02*j02;
    const float v02 = CC20*j00 + CC22*j02;
    const float v10 = CC01*j11 + CC02*j12;
    const float v11 = CC11*j11 + CC12*j12;
    const float v12 = CC21*j11 + CC22*j12;

    const float a  = j00*v00 + j02*v02 + 0.3f;
    const float b  = j00*v10 + j02*v12;
    const float cQ = j11*v11 + j12*v12 + 0.3f;

    const float det = a*cQ - b*b;
    const float det_safe = (det > 0.f) ? det : 1.f;
    const float conA =  cQ / det_safe;
    const float conB = -b  / det_safe;
    const float conC =  a  / det_safe;

    const bool  valid  = (z > 0.2f) && (det > 0.f);
    const float op_eff = valid ? opa[i] : 0.f;

    r0 = make_float4(mx, my, -0.5f*conA*LOG2E, -conB*LOG2E);
    r1 = make_float4(-0.5f*conC*LOG2E, op_eff, col[3*i], col[3*i+1]);
    r2 = col[3*i+2];
}

// ---------------------------------------------------------------------------
// Kernel 1: fused project + stable rank-sort + scatter.
// 16 blocks x 64 threads; each block computes ALL 1024 z's (cheap, redundant)
// into LDS, then fully projects + ranks + scatters its own 64 gaussians.
// ---------------------------------------------------------------------------
__global__ __launch_bounds__(64) void gs_prep(
    const float* __restrict__ pos, const float* __restrict__ cov,
    const float* __restrict__ col, const float* __restrict__ opa,
    const float* __restrict__ cm,
    float4* __restrict__ g0, float4* __restrict__ g1, float* __restrict__ g2)
{
    __shared__ float4 zsh4[NG / 4];
    float* zsh = (float*)zsh4;

    const int tid = threadIdx.x;
    const float R20 = cm[8], R21 = cm[9], R22 = cm[10], T2 = cm[11];

    #pragma unroll
    for (int q = 0; q < NG / 64; ++q) {
        const int g = q * 64 + tid;
        zsh[g] = R20*pos[3*g] + R21*pos[3*g+1] + R22*pos[3*g+2] + T2;
    }
    __syncthreads();

    const int i = blockIdx.x * 64 + tid;
    float4 r0, r1; float r2;
    project_one(i, pos, cov, col, opa, cm, r0, r1, r2);

    const float zi = zsh[i];
    int rank = 0;
    #pragma unroll 4
    for (int j4 = 0; j4 < NG / 4; ++j4) {
        const float4 v = zsh4[j4];
        const int j = 4 * j4;
        rank += (v.x < zi || (v.x == zi && j + 0 < i)) ? 1 : 0;
        rank += (v.y < zi || (v.y == zi && j + 1 < i)) ? 1 : 0;
        rank += (v.z < zi || (v.z == zi && j + 2 < i)) ? 1 : 0;
        rank += (v.w < zi || (v.w == zi && j + 3 < i)) ? 1 : 0;
    }
    g0[rank] = r0; g1[rank] = r1; g2[rank] = r2;
}

// ---------------------------------------------------------------------------
// Kernel 2: fused chunked raster + combine. 256 blocks x 1024 threads.
// Block = 64 pixels. Thread (c = tid>>4, jj = tid&15) composites gaussian
// chunk [16c, 16c+16) for 4 pixels {jj, jj+16, jj+32, jj+48}. Records are
// read from global (36 KB, L1/L2-hot). Per-(chunk,pixel) partials in 64 KB
// LDS; after barrier, 64 threads do the 64-step front-to-back chunk scan.
// ---------------------------------------------------------------------------
__global__ __launch_bounds__(1024) void gs_raster_combine(
    const float4* __restrict__ g0, const float4* __restrict__ g1,
    const float*  __restrict__ g2, float* __restrict__ out)
{
    __shared__ float4 part[64 * 64];     // [chunk][pixel] = 64 KB

    const int tid = threadIdx.x;
    const int c   = tid >> 4;            // chunk 0..63
    const int jj  = tid & 15;
    const int pxbase = blockIdx.x * 64;

    float pxf[4], pyf[4], T[4], cr[4], cg[4], cb[4];
    #pragma unroll
    for (int m = 0; m < 4; ++m) {
        const int p = pxbase + jj + m * 16;
        pxf[m] = (float)(p & (IMG_W - 1)) + 0.5f;
        pyf[m] = (float)(p >> 7) + 0.5f;
        T[m] = 1.f; cr[m] = 0.f; cg[m] = 0.f; cb[m] = 0.f;
    }

    const int base = c * 16;
    #pragma unroll 4
    for (int i = 0; i < 16; ++i) {
        const float4 A = g0[base + i];   // mx, my, a2, b2
        const float4 B = g1[base + i];   // c2, op, colR, colG
        const float  C = g2[base + i];
        #pragma unroll
        for (int m = 0; m < 4; ++m) {
            const float dx = pxf[m] - A.x;
            const float dy = pyf[m] - A.y;
            const float pw = fminf(A.z*dx*dx + B.x*dy*dy + A.w*(dx*dy), 0.f);
            const float G = __builtin_amdgcn_exp2f(pw);
            float alpha = fminf(B.y * G, 0.99f);
            alpha = (alpha >= MIN_A) ? alpha : 0.f;
            const float wT = alpha * T[m];
            cr[m] = fmaf(wT, B.z, cr[m]);
            cg[m] = fmaf(wT, B.w, cg[m]);
            cb[m] = fmaf(wT, C,   cb[m]);
            T[m] *= (1.f - alpha);
        }
    }

    #pragma unroll
    for (int m = 0; m < 4; ++m)
        part[c * 64 + jj + m * 16] = make_float4(cr[m], cg[m], cb[m], T[m]);

    __syncthreads();

    if (tid < 64) {                      // one thread per pixel: 64-chunk scan
        float Ts = 1.f, r = 0.f, g = 0.f, b = 0.f;
        #pragma unroll 8
        for (int k = 0; k < 64; ++k) {
            const float4 v = part[k * 64 + tid];
            r = fmaf(Ts, v.x, r);
            g = fmaf(Ts, v.y, g);
            b = fmaf(Ts, v.z, b);
            Ts *= v.w;
        }
        float* o = out + 3 * (pxbase + tid);
        o[0] = r; o[1] = g; o[2] = b;
    }
}

// ---------------------------------------------------------------------------
extern "C" void kernel_launch(void* const* d_in, const int* in_sizes, int n_in,
                              void* d_out, int out_size, void* d_ws, size_t ws_size,
                              hipStream_t stream) {
    const float* pos = (const float*)d_in[0];
    const float* cov = (const float*)d_in[1];
    const float* col = (const float*)d_in[2];
    const float* opa = (const float*)d_in[3];
    const float* cm  = (const float*)d_in[4];

    char* ws = (char*)d_ws;
    float4* g0 = (float4*)(ws);                 // 16384 B
    float4* g1 = (float4*)(ws + 16384);         // 16384 B
    float*  g2 = (float*) (ws + 32768);         //  4096 B

    gs_prep<<<NG / 64, 64, 0, stream>>>(pos, cov, col, opa, cm, g0, g1, g2);
    gs_raster_combine<<<NPIX / 64, 1024, 0, stream>>>(g0, g1, g2, (float*)d_out);
}